// Round 5
// baseline (507.058 us; speedup 1.0000x reference)
//
#include <hip/hip_runtime.h>
#include <math.h>

#define BB 4
#define NN 4096
#define DD 64
#define KK 8
#define NCH 3                   // unequal j-chunks: 11/11/10 double-tiles of 128 cols

#if defined(__has_builtin)
#if __has_builtin(__builtin_amdgcn_fmed3f)
#define FMED3(a, x, b) __builtin_amdgcn_fmed3f((x), (a), (b))
#endif
#endif
#ifndef FMED3
#define FMED3(a, x, b) fminf(fmaxf((a), (x)), (b))
#endif

__device__ __forceinline__ float tau_of(const float* __restrict__ temp) {
  float tc = temp[0];
  tc = fminf(fmaxf(tc, -5.0f), 5.0f);
  return expf(tc);
}

// Branch-free positional insert into sorted (ascending) top-8.
// All updates read OLD values -> fully parallel (no swap chain).
// key >= kk[7] is a no-op, so callers may gate with any thr <= kk[7].
// Equal keys place AFTER incumbents (correct for ascending-j arrival).
__device__ __forceinline__ void ins_med3(float (&kk)[KK], int (&kj)[KK], float key, int j) {
  const bool l0 = key < kk[0], l1 = key < kk[1], l2 = key < kk[2], l3 = key < kk[3];
  const bool l4 = key < kk[4], l5 = key < kk[5], l6 = key < kk[6], l7 = key < kk[7];
  kj[7] = l6 ? kj[6] : (l7 ? j : kj[7]);  kk[7] = FMED3(kk[6], key, kk[7]);
  kj[6] = l5 ? kj[5] : (l6 ? j : kj[6]);  kk[6] = FMED3(kk[5], key, kk[6]);
  kj[5] = l4 ? kj[4] : (l5 ? j : kj[5]);  kk[5] = FMED3(kk[4], key, kk[5]);
  kj[4] = l3 ? kj[3] : (l4 ? j : kj[4]);  kk[4] = FMED3(kk[3], key, kk[4]);
  kj[3] = l2 ? kj[2] : (l3 ? j : kj[3]);  kk[3] = FMED3(kk[2], key, kk[3]);
  kj[2] = l1 ? kj[1] : (l2 ? j : kj[2]);  kk[2] = FMED3(kk[1], key, kk[2]);
  kj[1] = l0 ? kj[0] : (l1 ? j : kj[1]);  kk[1] = FMED3(kk[0], key, kk[1]);
  kj[0] = l0 ? j : kj[0];                 kk[0] = fminf(kk[0], key);
}

// Lexicographic (key asc, idx asc) branch-free insert — arrival-order independent.
__device__ __forceinline__ void ins_lexm(float (&kk)[KK], int (&kj)[KK], float key, int j) {
  bool l[KK];
#pragma unroll
  for (int m = 0; m < KK; ++m)
    l[m] = (key < kk[m]) || (key == kk[m] && j < kj[m]);
  kj[7] = l[6] ? kj[6] : (l[7] ? j : kj[7]);  kk[7] = FMED3(kk[6], key, kk[7]);
  kj[6] = l[5] ? kj[5] : (l[6] ? j : kj[6]);  kk[6] = FMED3(kk[5], key, kk[6]);
  kj[5] = l[4] ? kj[4] : (l[5] ? j : kj[5]);  kk[5] = FMED3(kk[4], key, kk[5]);
  kj[4] = l[3] ? kj[3] : (l[4] ? j : kj[4]);  kk[4] = FMED3(kk[3], key, kk[4]);
  kj[3] = l[2] ? kj[2] : (l[3] ? j : kj[3]);  kk[3] = FMED3(kk[2], key, kk[3]);
  kj[2] = l[1] ? kj[1] : (l[2] ? j : kj[2]);  kk[2] = FMED3(kk[1], key, kk[2]);
  kj[1] = l[0] ? kj[0] : (l[1] ? j : kj[1]);  kk[1] = FMED3(kk[0], key, kk[1]);
  kj[0] = l[0] ? j : kj[0];                   kk[0] = fminf(kk[0], key);
}

// ---------------- Kernel 1: MLP (3 layers) + row squared norms ----------------
__device__ __forceinline__ void mlp_layer(const float (*bin)[68], float (*bout)[68],
                                          float (*wT)[68], float* bias,
                                          const float* __restrict__ Wg,
                                          const float* __restrict__ bg,
                                          bool dorelu, int t) {
  const int rr = t >> 2;
  const int dc = (t & 3) << 4;
  {
    const float* wsrc = Wg + rr * DD + dc;
#pragma unroll
    for (int q = 0; q < 16; ++q) wT[dc + q][rr] = wsrc[q];  // wT[i][o] = W[o][i]
    if (t < DD) bias[t] = bg[t];
  }
  __syncthreads();
  const int tg = t & 15, og = t >> 4;
  float acc[4][4];
#pragma unroll
  for (int r = 0; r < 4; ++r)
#pragma unroll
    for (int c = 0; c < 4; ++c) acc[r][c] = 0.f;
#pragma unroll 4
  for (int i = 0; i < DD; ++i) {
    const float4 av = *reinterpret_cast<const float4*>(&bin[i][tg << 2]);
    const float4 wv = *reinterpret_cast<const float4*>(&wT[i][og << 2]);
    float aa[4] = {av.x, av.y, av.z, av.w};
    float ww[4] = {wv.x, wv.y, wv.z, wv.w};
#pragma unroll
    for (int r = 0; r < 4; ++r)
#pragma unroll
      for (int c = 0; c < 4; ++c) acc[r][c] += aa[r] * ww[c];
  }
#pragma unroll
  for (int r = 0; r < 4; ++r)
#pragma unroll
    for (int c = 0; c < 4; ++c) {
      float v = acc[r][c] + bias[(og << 2) + c];
      if (dorelu) v = fmaxf(v, 0.f);
      bout[(og << 2) + c][(tg << 2) + r] = v;  // transposed for next layer
    }
  __syncthreads();
}

__global__ __launch_bounds__(256) void k_mlp(
    const float* __restrict__ x,
    const float* __restrict__ W1, const float* __restrict__ b1,
    const float* __restrict__ W2, const float* __restrict__ b2,
    const float* __restrict__ W3, const float* __restrict__ b3,
    float* __restrict__ h, float* __restrict__ sqo) {
  __shared__ float bufA[DD][68];
  __shared__ float bufB[DD][68];
  __shared__ float wT[DD][68];
  __shared__ float bias[DD];
  const int t = threadIdx.x;
  const size_t tok0 = (size_t)blockIdx.x * 64;
  const int rr = t >> 2;
  const int dc = (t & 3) << 4;
  {
    const float* src = x + (tok0 + rr) * DD + dc;
#pragma unroll
    for (int q = 0; q < 16; ++q) bufA[dc + q][rr] = src[q];
  }
  mlp_layer(bufA, bufB, wT, bias, W1, b1, true, t);
  mlp_layer(bufB, bufA, wT, bias, W2, b2, true, t);
  mlp_layer(bufA, bufB, wT, bias, W3, b3, false, t);
  {
    float s = 0.f;
    float* dst = h + (tok0 + rr) * DD + dc;
#pragma unroll
    for (int q = 0; q < 16; ++q) {
      float v = bufB[dc + q][rr];
      dst[q] = v;
      s += v * v;
    }
    s += __shfl_xor(s, 1);
    s += __shfl_xor(s, 2);
    if ((t & 3) == 0) sqo[tok0 + rr] = s;
  }
}

// ---- Kernel 2 helper: 3-stage per-row merge of the 16 lane-lists (one row slice) ----
__device__ __forceinline__ void merge_pass(
    char* smem, int t, int roff, int b, int i0, int ch,
    float (&kkx)[KK], int (&kjx)[KK],
    float* __restrict__ pk, int* __restrict__ pj) {
  float* dK = (float*)(smem);            // [16 rows][16 lists][8]  8KB
  int* dJ = (int*)(smem + 8192);         // 8KB
  float* oK = (float*)(smem + 16384);    // [16 rows][4][8] 2KB
  int* oJ = (int*)(smem + 16384 + 2048); // 2KB
  const int rg = t >> 4, cg = t & 15;
  __syncthreads();  // previous phase's readers (GEMM or prior pass stage B) done
#pragma unroll
  for (int m = 0; m < KK; ++m) {
    dK[(rg * 16 + cg) * KK + m] = kkx[m];
    dJ[(rg * 16 + cg) * KK + m] = kjx[m];
  }
  __syncthreads();
  if (t < 64) {
    const int row16 = t >> 2, q = t & 3;
    float fk[KK]; int fj[KK];
#pragma unroll
    for (int m = 0; m < KK; ++m) { fk[m] = 3.0e38f; fj[m] = 0x7fffffff; }
#pragma unroll
    for (int o = 0; o < 4; ++o)
#pragma unroll
      for (int m = 0; m < KK; ++m)
        ins_lexm(fk, fj, dK[(row16 * 16 + q * 4 + o) * KK + m],
                         dJ[(row16 * 16 + q * 4 + o) * KK + m]);
#pragma unroll
    for (int m = 0; m < KK; ++m) {
      oK[(row16 * 4 + q) * KK + m] = fk[m];
      oJ[(row16 * 4 + q) * KK + m] = fj[m];
    }
  }
  __syncthreads();
  if (t < 16) {
    float gk[KK]; int gj[KK];
#pragma unroll
    for (int m = 0; m < KK; ++m) { gk[m] = 3.0e38f; gj[m] = 0x7fffffff; }
#pragma unroll
    for (int q = 0; q < 4; ++q)
#pragma unroll
      for (int m = 0; m < KK; ++m)
        ins_lexm(gk, gj, oK[(t * 4 + q) * KK + m], oJ[(t * 4 + q) * KK + m]);
    const size_t base = ((size_t)(b * NN + i0 + (t << 2) + roff) * NCH + ch) * KK;
#pragma unroll
    for (int m = 0; m < KK; ++m) { pk[base + m] = gk[m]; pj[base + m] = gj[m]; }
  }
}

// ------- Kernel 2: 64x128 double-tiles, 4x8 register tile, gray-swizzled hjT -------
__global__ __launch_bounds__(256, 3) void k_disttopk(
    const float* __restrict__ h, const float* __restrict__ sq,
    const float* __restrict__ temp,
    float* __restrict__ pk, int* __restrict__ pj) {
  // LDS: hiT [64][64] @0 (16KB) | hjT [64][128] gray-block-swizzled @16384 (32KB)
  //      sqjS [128] @49152. Merge passes reuse the first 20.5KB.
  __shared__ __align__(16) char smem[16384 + 32768 + 512];
  float (*hiT)[64] = (float (*)[64])(smem);
  float* hjT = (float*)(smem + 16384);
  float* sqjS = (float*)(smem + 49152);

  const int t = threadIdx.x;
  const int bx = blockIdx.x;
  const int b = bx / 192;
  const int rem = bx % 192;
  const int rt = rem / 3;
  const int ch = rem % 3;
  const int i0 = rt << 6;
  const int dt0 = (ch == 0) ? 0 : ((ch == 1) ? 11 : 22);
  const int dt1 = (ch == 0) ? 11 : ((ch == 1) ? 22 : 32);
  const float* hb = h + (size_t)b * NN * DD;
  const float* sqb = sq + b * NN;
  const float tau = tau_of(temp);

  const int rg = t >> 4, cg = t & 15;
  const int r0 = rg << 2;               // 4 rows per thread
  const int c0 = cg << 3;               // 8 logical cols per thread
  // gray-swizzled physical float offsets of the two b128 col-blocks
  const int pb0 = (((2 * cg) ^ cg) << 2);
  const int pb1 = (((2 * cg + 1) ^ cg) << 2);

  // ---- stage hiT (conflict-free: lane tok = t&63 -> bank tok%32 2-way) ----
  {
    const int tok = t & 63, dch = t >> 6;  // 16 floats of one token
    const float* src = hb + (size_t)(i0 + tok) * DD + (dch << 4);
    const float4 f0 = *(const float4*)(src);
    const float4 f1 = *(const float4*)(src + 4);
    const float4 f2 = *(const float4*)(src + 8);
    const float4 f3 = *(const float4*)(src + 12);
    const int d0 = dch << 4;
    hiT[d0 + 0][tok] = f0.x; hiT[d0 + 1][tok] = f0.y; hiT[d0 + 2][tok] = f0.z; hiT[d0 + 3][tok] = f0.w;
    hiT[d0 + 4][tok] = f1.x; hiT[d0 + 5][tok] = f1.y; hiT[d0 + 6][tok] = f1.z; hiT[d0 + 7][tok] = f1.w;
    hiT[d0 + 8][tok] = f2.x; hiT[d0 + 9][tok] = f2.y; hiT[d0 + 10][tok] = f2.z; hiT[d0 + 11][tok] = f2.w;
    hiT[d0 + 12][tok] = f3.x; hiT[d0 + 13][tok] = f3.y; hiT[d0 + 14][tok] = f3.z; hiT[d0 + 15][tok] = f3.w;
  }
  float sqi0 = sqb[i0 + r0 + 0];
  float sqi1 = sqb[i0 + r0 + 1];
  float sqi2 = sqb[i0 + r0 + 2];
  float sqi3 = sqb[i0 + r0 + 3];

  float kk0[KK], kk1[KK], kk2[KK], kk3[KK];
  int kj0[KK], kj1[KK], kj2[KK], kj3[KK];
#pragma unroll
  for (int m = 0; m < KK; ++m) {
    kk0[m] = 3.0e38f; kj0[m] = 0x7fffffff;
    kk1[m] = 3.0e38f; kj1[m] = 0x7fffffff;
    kk2[m] = 3.0e38f; kj2[m] = 0x7fffffff;
    kk3[m] = 3.0e38f; kj3[m] = 0x7fffffff;
  }

  // staging indices for hjT: lane stages 32 d-floats of one token
  const int tokJ = t & 127;
  const int dchJ = t >> 7;  // 0..1 -> d = dchJ*32 .. +31
  const int cbJ = tokJ >> 2;
  const int pcol = (((cbJ ^ (cbJ >> 1)) << 2) | (tokJ & 3));  // gray block swizzle

  for (int dt = dt0; dt < dt1; ++dt) {
    const int j0 = dt << 7;
    __syncthreads();  // previous tile's readers done (also covers initial hiT stage)
    {
      const float* src = hb + (size_t)(j0 + tokJ) * DD + (dchJ << 5);
      float4 f[8];
#pragma unroll
      for (int q = 0; q < 8; ++q) f[q] = *(const float4*)(src + (q << 2));
      const int dbase = dchJ << 5;
#pragma unroll
      for (int q = 0; q < 8; ++q) {
        hjT[(size_t)(dbase + (q << 2) + 0) * 128 + pcol] = f[q].x;
        hjT[(size_t)(dbase + (q << 2) + 1) * 128 + pcol] = f[q].y;
        hjT[(size_t)(dbase + (q << 2) + 2) * 128 + pcol] = f[q].z;
        hjT[(size_t)(dbase + (q << 2) + 3) * 128 + pcol] = f[q].w;
      }
      if (t < 128) sqjS[t] = sqb[j0 + t];
    }
    __syncthreads();

    // per-row threshold = min over the 16 lanes sharing these rows of kk[7]
    float th0 = kk0[7], th1 = kk1[7], th2 = kk2[7], th3 = kk3[7];
#pragma unroll
    for (int msk = 1; msk <= 8; msk <<= 1) {
      th0 = fminf(th0, __shfl_xor(th0, msk));
      th1 = fminf(th1, __shfl_xor(th1, msk));
      th2 = fminf(th2, __shfl_xor(th2, msk));
      th3 = fminf(th3, __shfl_xor(th3, msk));
    }

    float acc[4][8];
#pragma unroll
    for (int r = 0; r < 4; ++r)
#pragma unroll
      for (int c = 0; c < 8; ++c) acc[r][c] = 0.f;
    {
      const float* pA = &hiT[0][r0];
      const float* pB0 = hjT + pb0;
      const float* pB1 = hjT + pb1;
#pragma unroll 4
      for (int d = 0; d < DD; ++d) {
        const float4 av = *(const float4*)(pA);
        const float4 b0v = *(const float4*)(pB0);
        const float4 b1v = *(const float4*)(pB1);
        pA += 64; pB0 += 128; pB1 += 128;
        const float aa[4] = {av.x, av.y, av.z, av.w};
        const float bb[8] = {b0v.x, b0v.y, b0v.z, b0v.w, b1v.x, b1v.y, b1v.z, b1v.w};
#pragma unroll
        for (int r = 0; r < 4; ++r)
#pragma unroll
          for (int c = 0; c < 8; ++c) acc[r][c] += aa[r] * bb[c];
      }
    }
    // epilogue: key = fl(fl(fl(sqi+sqj) - fl(2*dot)) * tau), filtered insert
    const float4 sj0v = *(const float4*)(&sqjS[c0]);
    const float4 sj1v = *(const float4*)(&sqjS[c0 + 4]);
    const float sj[8] = {sj0v.x, sj0v.y, sj0v.z, sj0v.w, sj1v.x, sj1v.y, sj1v.z, sj1v.w};
#pragma unroll
    for (int c = 0; c < 8; ++c) {
      const int j = j0 + c0 + c;
      {
        float key = __fmul_rn(__fsub_rn(__fadd_rn(sqi0, sj[c]), __fmul_rn(2.0f, acc[0][c])), tau);
        if (key < th0) ins_med3(kk0, kj0, key, j);
      }
      {
        float key = __fmul_rn(__fsub_rn(__fadd_rn(sqi1, sj[c]), __fmul_rn(2.0f, acc[1][c])), tau);
        if (key < th1) ins_med3(kk1, kj1, key, j);
      }
      {
        float key = __fmul_rn(__fsub_rn(__fadd_rn(sqi2, sj[c]), __fmul_rn(2.0f, acc[2][c])), tau);
        if (key < th2) ins_med3(kk2, kj2, key, j);
      }
      {
        float key = __fmul_rn(__fsub_rn(__fadd_rn(sqi3, sj[c]), __fmul_rn(2.0f, acc[3][c])), tau);
        if (key < th3) ins_med3(kk3, kj3, key, j);
      }
    }
  }

  // ---- merge: 4 passes (one per thread-row), 16 lists -> 1 per row ----
  merge_pass(smem, t, 0, b, i0, ch, kk0, kj0, pk, pj);
  merge_pass(smem, t, 1, b, i0, ch, kk1, kj1, pk, pj);
  merge_pass(smem, t, 2, b, i0, ch, kk2, kj2, pk, pj);
  merge_pass(smem, t, 3, b, i0, ch, kk3, kj3, pk, pj);
}

// ------- Kernel 3: merge chunks, recompute dng, emit edges + logprobs -------
__global__ __launch_bounds__(256) void k_final(
    const float* __restrict__ h, const float* __restrict__ pk,
    const int* __restrict__ pj, const float* __restrict__ temp,
    float* __restrict__ out) {
  const int gid = blockIdx.x * 256 + threadIdx.x;  // 0..B*N-1
  const int b = gid >> 12;
  const int i = gid & (NN - 1);
  const float tau = tau_of(temp);

  float fk[KK]; int fj[KK];
#pragma unroll
  for (int m = 0; m < KK; ++m) { fk[m] = 3.0e38f; fj[m] = 0x7fffffff; }
  const size_t base = (size_t)(b * NN + i) * NCH * KK;
#pragma unroll
  for (int s = 0; s < NCH * KK; ++s) {
    ins_lexm(fk, fj, pk[base + s], pj[base + s]);
  }

  const float* hi = h + (size_t)(b * NN + i) * DD;
  float4 xi[16];
#pragma unroll
  for (int q = 0; q < 16; ++q) xi[q] = *reinterpret_cast<const float4*>(hi + (q << 2));

  float* oute = out;
  float* outl = out + (size_t)BB * NN * KK * 2;
#pragma unroll
  for (int m = 0; m < KK; ++m) {
    const int j = fj[m];
    const float* hj = h + (size_t)(b * NN + j) * DD;
    float dng = 0.f;
#pragma unroll
    for (int q = 0; q < 16; ++q) {
      const float4 vj = *reinterpret_cast<const float4*>(hj + (q << 2));
      float dx = xi[q].x - vj.x; dng += dx * dx;
      float dy = xi[q].y - vj.y; dng += dy * dy;
      float dz = xi[q].z - vj.z; dng += dz * dz;
      float dw = xi[q].w - vj.w; dng += dw * dw;
    }
    const size_t e = (size_t)(b * NN + i) * KK + m;
    oute[e * 2 + 0] = (float)j;
    oute[e * 2 + 1] = (float)i;
    outl[e] = -__fmul_rn(dng, tau);
  }
}

extern "C" void kernel_launch(void* const* d_in, const int* in_sizes, int n_in,
                              void* d_out, int out_size, void* d_ws, size_t ws_size,
                              hipStream_t stream) {
  const float* x  = (const float*)d_in[0];
  const float* W1 = (const float*)d_in[1];
  const float* b1 = (const float*)d_in[2];
  const float* W2 = (const float*)d_in[3];
  const float* b2 = (const float*)d_in[4];
  const float* W3 = (const float*)d_in[5];
  const float* b3 = (const float*)d_in[6];
  const float* temp = (const float*)d_in[7];
  (void)in_sizes; (void)n_in; (void)out_size; (void)ws_size;

  float* ws = (float*)d_ws;
  float* h  = ws;                                        // B*N*D
  float* sq = h + (size_t)BB * NN * DD;                  // B*N
  float* pk = sq + (size_t)BB * NN;                      // B*N*NCH*K
  int*   pj = (int*)(pk + (size_t)BB * NN * NCH * KK);   // B*N*NCH*K
  float* out = (float*)d_out;

  k_mlp<<<BB * NN / 64, 256, 0, stream>>>(x, W1, b1, W2, b2, W3, b3, h, sq);
  k_disttopk<<<BB * 64 * NCH, 256, 0, stream>>>(h, sq, temp, pk, pj);
  k_final<<<BB * NN / 256, 256, 0, stream>>>(h, pk, pj, temp, out);
}

// Round 6
// 308.269 us; speedup vs baseline: 1.6449x; 1.6449x over previous
//
#include <hip/hip_runtime.h>
#include <math.h>

#define BB 4
#define NN 4096
#define DD 64
#define KK 8
#define CH 4                    // j-chunks per row: grid = 4*64*4 = 1024 blocks
#define NT ((NN / CH) / 64)     // 16 j-tiles per block

__device__ __forceinline__ float tau_of(const float* __restrict__ temp) {
  float tc = temp[0];
  tc = fminf(fmaxf(tc, -5.0f), 5.0f);
  return expf(tc);
}

// insert into sorted (ascending key) top-8; strict < => on equal keys the
// earlier-arrived (smaller j, given ascending-j arrival) entry stays ahead.
// NOTE: reference-to-1-D-array signature is load-bearing: pointer-decay off
// 2-D arrays blocked SROA in rounds 2/3 -> 300 MB of scratch traffic.
__device__ __forceinline__ void ins_strict(float (&kk)[KK], int (&kj)[KK], float key, int j) {
  if (key < kk[KK - 1]) {
    kk[KK - 1] = key; kj[KK - 1] = j;
#pragma unroll
    for (int m = KK - 1; m > 0; --m) {
      if (kk[m] < kk[m - 1]) {
        float tk = kk[m]; kk[m] = kk[m - 1]; kk[m - 1] = tk;
        int tj = kj[m]; kj[m] = kj[m - 1]; kj[m - 1] = tj;
      }
    }
  }
}

// lexicographic (key asc, idx asc) insertion — arrival order independent.
__device__ __forceinline__ void ins_lex(float (&kk)[KK], int (&kj)[KK], float key, int j) {
  if (key < kk[KK - 1] || (key == kk[KK - 1] && j < kj[KK - 1])) {
    kk[KK - 1] = key; kj[KK - 1] = j;
#pragma unroll
    for (int m = KK - 1; m > 0; --m) {
      bool sw = (kk[m] < kk[m - 1]) || (kk[m] == kk[m - 1] && kj[m] < kj[m - 1]);
      if (sw) {
        float tk = kk[m]; kk[m] = kk[m - 1]; kk[m - 1] = tk;
        int tj = kj[m]; kj[m] = kj[m - 1]; kj[m - 1] = tj;
      }
    }
  }
}

__device__ __forceinline__ void scatter16(float (*dst)[64], int dc, int col,
                                          const float4& a, const float4& b,
                                          const float4& c, const float4& d) {
  dst[dc + 0][col] = a.x; dst[dc + 1][col] = a.y; dst[dc + 2][col] = a.z; dst[dc + 3][col] = a.w;
  dst[dc + 4][col] = b.x; dst[dc + 5][col] = b.y; dst[dc + 6][col] = b.z; dst[dc + 7][col] = b.w;
  dst[dc + 8][col] = c.x; dst[dc + 9][col] = c.y; dst[dc + 10][col] = c.z; dst[dc + 11][col] = c.w;
  dst[dc + 12][col] = d.x; dst[dc + 13][col] = d.y; dst[dc + 14][col] = d.z; dst[dc + 15][col] = d.w;
}

// ---------------- Kernel 1: MLP (3 layers) + row squared norms ----------------
__device__ __forceinline__ void mlp_layer(const float (*bin)[68], float (*bout)[68],
                                          float (*wT)[68], float* bias,
                                          const float* __restrict__ Wg,
                                          const float* __restrict__ bg,
                                          bool dorelu, int t) {
  const int rr = t >> 2;
  const int dc = (t & 3) << 4;
  {
    const float* wsrc = Wg + rr * DD + dc;
#pragma unroll
    for (int q = 0; q < 16; ++q) wT[dc + q][rr] = wsrc[q];  // wT[i][o] = W[o][i]
    if (t < DD) bias[t] = bg[t];
  }
  __syncthreads();
  const int tg = t & 15, og = t >> 4;
  float acc[4][4];
#pragma unroll
  for (int r = 0; r < 4; ++r)
#pragma unroll
    for (int c = 0; c < 4; ++c) acc[r][c] = 0.f;
#pragma unroll 4
  for (int i = 0; i < DD; ++i) {
    const float4 av = *reinterpret_cast<const float4*>(&bin[i][tg << 2]);
    const float4 wv = *reinterpret_cast<const float4*>(&wT[i][og << 2]);
    float aa[4] = {av.x, av.y, av.z, av.w};
    float ww[4] = {wv.x, wv.y, wv.z, wv.w};
#pragma unroll
    for (int r = 0; r < 4; ++r)
#pragma unroll
      for (int c = 0; c < 4; ++c) acc[r][c] += aa[r] * ww[c];
  }
#pragma unroll
  for (int r = 0; r < 4; ++r)
#pragma unroll
    for (int c = 0; c < 4; ++c) {
      float v = acc[r][c] + bias[(og << 2) + c];
      if (dorelu) v = fmaxf(v, 0.f);
      bout[(og << 2) + c][(tg << 2) + r] = v;  // transposed for next layer
    }
  __syncthreads();
}

__global__ __launch_bounds__(256) void k_mlp(
    const float* __restrict__ x,
    const float* __restrict__ W1, const float* __restrict__ b1,
    const float* __restrict__ W2, const float* __restrict__ b2,
    const float* __restrict__ W3, const float* __restrict__ b3,
    float* __restrict__ h, float* __restrict__ sqo) {
  __shared__ float bufA[DD][68];
  __shared__ float bufB[DD][68];
  __shared__ float wT[DD][68];
  __shared__ float bias[DD];
  const int t = threadIdx.x;
  const size_t tok0 = (size_t)blockIdx.x * 64;
  const int rr = t >> 2;
  const int dc = (t & 3) << 4;
  {
    const float* src = x + (tok0 + rr) * DD + dc;
#pragma unroll
    for (int q = 0; q < 16; ++q) bufA[dc + q][rr] = src[q];
  }
  mlp_layer(bufA, bufB, wT, bias, W1, b1, true, t);
  mlp_layer(bufB, bufA, wT, bias, W2, b2, true, t);
  mlp_layer(bufA, bufB, wT, bias, W3, b3, false, t);
  {
    float s = 0.f;
    float* dst = h + (tok0 + rr) * DD + dc;
#pragma unroll
    for (int q = 0; q < 16; ++q) {
      float v = bufB[dc + q][rr];
      dst[q] = v;
      s += v * v;
    }
    s += __shfl_xor(s, 1);
    s += __shfl_xor(s, 2);
    if ((t & 3) == 0) sqo[tok0 + rr] = s;
  }
}

// ------- Kernel 2: fused distance tiles + per-row top-8, register lists -------
// 2x8 register tile per thread: 2 rows (r0, r0+1) x 8 cols (c0..c0+7).
// Two named top-8 lists per thread (kkA/kjA for r0, kkB/kjB for r0+1).
// Row-global threshold gate: thA/thB = min over the 8 lanes sharing the row
// pair of kk[7], refreshed once per tile (stale-within-tile = permissive = safe).
__global__ __launch_bounds__(256, 3) void k_disttopk(
    const float* __restrict__ h, const float* __restrict__ sq,
    const float* __restrict__ temp,
    float* __restrict__ pk, int* __restrict__ pj) {
  // LDS (33 KB -> 4 blocks/CU): hiT [64][64] @0 | hjT [64][64] @16384 | sqj @32768
  // merge reuse: dK @0 (16KB), dJ @16384 (16KB); then oK @0 (4KB), oJ @4096 (4KB)
  __shared__ __align__(16) char smem[16384 + 16384 + 256];
  float (*hiT)[64] = (float (*)[64])(smem);
  float (*hjT)[64] = (float (*)[64])(smem + 16384);
  float* sqjS = (float*)(smem + 32768);  // [64]

  const int t = threadIdx.x;
  const int bx = blockIdx.x;
  const int b = bx >> 8;
  const int rem = bx & 255;
  const int rt = rem >> 2;
  const int ch = rem & 3;
  const int i0 = rt << 6;
  const int jbase = ch * (NN / CH);
  const float* hb = h + (size_t)b * NN * DD;
  const float* sqb = sq + b * NN;
  const float tau = tau_of(temp);

  const int rg = t >> 3;        // 0..31
  const int cg = t & 7;         // 0..7
  const int r0 = rg << 1;       // even row
  const int c0 = cg << 3;       // col block of 8
  const int rr = t >> 2;        // staging: token within tile
  const int dc = (t & 3) << 4;  // staging: 16-float chunk

  // stage hiT and tile 0 of hjT (transposed [d][tok])
  {
    const float* src = hb + (size_t)(i0 + rr) * DD + dc;
    float4 f0 = *(const float4*)(src);
    float4 f1 = *(const float4*)(src + 4);
    float4 f2 = *(const float4*)(src + 8);
    float4 f3 = *(const float4*)(src + 12);
    scatter16(hiT, dc, rr, f0, f1, f2, f3);
  }
  {
    const float* src = hb + (size_t)(jbase + rr) * DD + dc;
    float4 f0 = *(const float4*)(src);
    float4 f1 = *(const float4*)(src + 4);
    float4 f2 = *(const float4*)(src + 8);
    float4 f3 = *(const float4*)(src + 12);
    scatter16(hjT, dc, rr, f0, f1, f2, f3);
    if (t < 64) sqjS[t] = sqb[jbase + t];
  }
  const float sqi0 = sqb[i0 + r0];
  const float sqi1 = sqb[i0 + r0 + 1];

  float kkA[KK]; int kjA[KK];
  float kkB[KK]; int kjB[KK];
#pragma unroll
  for (int m = 0; m < KK; ++m) {
    kkA[m] = 3.0e38f; kjA[m] = 0x7fffffff;
    kkB[m] = 3.0e38f; kjB[m] = 0x7fffffff;
  }

  __syncthreads();

  for (int jt = 0; jt < NT; ++jt) {
    const int j0 = jbase + (jt << 6);

    // T14: issue next tile's global loads now; LDS write after the compute+barrier
    float4 pf0, pf1, pf2, pf3; float psq = 0.f;
    const bool hasNext = (jt + 1 < NT);
    if (hasNext) {
      const float* src = hb + (size_t)(j0 + 64 + rr) * DD + dc;
      pf0 = *(const float4*)(src);
      pf1 = *(const float4*)(src + 4);
      pf2 = *(const float4*)(src + 8);
      pf3 = *(const float4*)(src + 12);
      if (t < 64) psq = sqb[j0 + 64 + t];
    }

    // row-global thresholds: min of kk[7] over the 8 lanes sharing the rows
    float thA = kkA[KK - 1], thB = kkB[KK - 1];
    thA = fminf(thA, __shfl_xor(thA, 1));
    thA = fminf(thA, __shfl_xor(thA, 2));
    thA = fminf(thA, __shfl_xor(thA, 4));
    thB = fminf(thB, __shfl_xor(thB, 1));
    thB = fminf(thB, __shfl_xor(thB, 2));
    thB = fminf(thB, __shfl_xor(thB, 4));

    float acc[2][8];
#pragma unroll
    for (int r = 0; r < 2; ++r)
#pragma unroll
      for (int c = 0; c < 8; ++c) acc[r][c] = 0.f;
#pragma unroll 8
    for (int d = 0; d < DD; ++d) {
      const float2 a2 = *(const float2*)(&hiT[d][r0]);
      const float4 b0 = *(const float4*)(&hjT[d][c0]);
      const float4 b1 = *(const float4*)(&hjT[d][c0 + 4]);
      float bb[8] = {b0.x, b0.y, b0.z, b0.w, b1.x, b1.y, b1.z, b1.w};
#pragma unroll
      for (int c = 0; c < 8; ++c) {
        acc[0][c] += a2.x * bb[c];
        acc[1][c] += a2.y * bb[c];
      }
    }
    // epilogue: dist -> key -> gated per-row register top-8 (ascending j)
    const float4 sj0 = *(const float4*)(&sqjS[c0]);
    const float4 sj1 = *(const float4*)(&sqjS[c0 + 4]);
    float sj[8] = {sj0.x, sj0.y, sj0.z, sj0.w, sj1.x, sj1.y, sj1.z, sj1.w};
#pragma unroll
    for (int c = 0; c < 8; ++c) {
      const int j = j0 + c0 + c;
      float d0 = __fsub_rn(__fadd_rn(sqi0, sj[c]), __fmul_rn(2.0f, acc[0][c]));
      float keyA = __fmul_rn(d0, tau);
      if (keyA < thA) ins_strict(kkA, kjA, keyA, j);
      float d1 = __fsub_rn(__fadd_rn(sqi1, sj[c]), __fmul_rn(2.0f, acc[1][c]));
      float keyB = __fmul_rn(d1, tau);
      if (keyB < thB) ins_strict(kkB, kjB, keyB, j);
    }
    __syncthreads();  // everyone done reading hjT/sqjS
    if (hasNext) {
      scatter16(hjT, dc, rr, pf0, pf1, pf2, pf3);
      if (t < 64) sqjS[t] = psq;
    }
    __syncthreads();  // staged tile visible
  }

  // ---- merge per-row across the 8 cg-lists ----
  float* dK = (float*)(smem);            // [64][8][8] keys (16KB)
  int*   dJ = (int*)(smem + 16384);      // [64][8][8] idx  (16KB)
  // dump (hiT/hjT no longer needed; loop-end barrier covers us)
#pragma unroll
  for (int m = 0; m < KK; ++m) {
    dK[(r0 * 8 + cg) * KK + m] = kkA[m];
    dJ[(r0 * 8 + cg) * KK + m] = kjA[m];
    dK[((r0 + 1) * 8 + cg) * KK + m] = kkB[m];
    dJ[((r0 + 1) * 8 + cg) * KK + m] = kjB[m];
  }
  __syncthreads();

  // stage A: 128 threads, each merges 4 lists of one (row, half)
  float fk[KK]; int fj[KK];
#pragma unroll
  for (int m = 0; m < KK; ++m) { fk[m] = 3.0e38f; fj[m] = 0x7fffffff; }
  const int rowA = t >> 1, half = t & 1;
  if (t < 128) {
#pragma unroll
    for (int o = 0; o < 4; ++o) {
#pragma unroll
      for (int m = 0; m < KK; ++m) {
        ins_lex(fk, fj, dK[(rowA * 8 + half * 4 + o) * KK + m],
                        dJ[(rowA * 8 + half * 4 + o) * KK + m]);
      }
    }
  }
  __syncthreads();  // stage-A reads complete before overwrite
  float* oK = (float*)(smem);            // [64][2][8] keys (4KB)
  int*   oJ = (int*)(smem + 4096);       // [64][2][8] idx  (4KB)
  if (t < 128) {
#pragma unroll
    for (int m = 0; m < KK; ++m) {
      oK[(rowA * 2 + half) * KK + m] = fk[m];
      oJ[(rowA * 2 + half) * KK + m] = fj[m];
    }
  }
  __syncthreads();

  // stage B: 64 threads, merge the 2 halves, write out
  if (t < 64) {
    float gk[KK]; int gj[KK];
#pragma unroll
    for (int m = 0; m < KK; ++m) { gk[m] = 3.0e38f; gj[m] = 0x7fffffff; }
#pragma unroll
    for (int q = 0; q < 2; ++q) {
#pragma unroll
      for (int m = 0; m < KK; ++m) {
        ins_lex(gk, gj, oK[(t * 2 + q) * KK + m], oJ[(t * 2 + q) * KK + m]);
      }
    }
    const size_t base = ((size_t)(b * NN + i0 + t) * CH + ch) * KK;
#pragma unroll
    for (int m = 0; m < KK; ++m) { pk[base + m] = gk[m]; pj[base + m] = gj[m]; }
  }
}

// ------- Kernel 3: merge chunks, recompute dng, emit edges + logprobs -------
__global__ __launch_bounds__(256) void k_final(
    const float* __restrict__ h, const float* __restrict__ pk,
    const int* __restrict__ pj, const float* __restrict__ temp,
    float* __restrict__ out) {
  const int gid = blockIdx.x * 256 + threadIdx.x;  // 0..B*N-1
  const int b = gid >> 12;
  const int i = gid & (NN - 1);
  const float tau = tau_of(temp);

  float fk[KK]; int fj[KK];
#pragma unroll
  for (int m = 0; m < KK; ++m) { fk[m] = 3.0e38f; fj[m] = 0x7fffffff; }
  const size_t base = (size_t)(b * NN + i) * CH * KK;
#pragma unroll
  for (int s = 0; s < CH * KK; ++s) {
    ins_lex(fk, fj, pk[base + s], pj[base + s]);
  }

  const float* hi = h + (size_t)(b * NN + i) * DD;
  float4 xi[16];
#pragma unroll
  for (int q = 0; q < 16; ++q) xi[q] = *reinterpret_cast<const float4*>(hi + (q << 2));

  float* oute = out;
  float* outl = out + (size_t)BB * NN * KK * 2;
#pragma unroll
  for (int m = 0; m < KK; ++m) {
    const int j = fj[m];
    const float* hj = h + (size_t)(b * NN + j) * DD;
    float dng = 0.f;
#pragma unroll
    for (int q = 0; q < 16; ++q) {
      const float4 vj = *reinterpret_cast<const float4*>(hj + (q << 2));
      float dx = xi[q].x - vj.x; dng += dx * dx;
      float dy = xi[q].y - vj.y; dng += dy * dy;
      float dz = xi[q].z - vj.z; dng += dz * dz;
      float dw = xi[q].w - vj.w; dng += dw * dw;
    }
    const size_t e = (size_t)(b * NN + i) * KK + m;
    oute[e * 2 + 0] = (float)j;
    oute[e * 2 + 1] = (float)i;
    outl[e] = -__fmul_rn(dng, tau);
  }
}

extern "C" void kernel_launch(void* const* d_in, const int* in_sizes, int n_in,
                              void* d_out, int out_size, void* d_ws, size_t ws_size,
                              hipStream_t stream) {
  const float* x  = (const float*)d_in[0];
  const float* W1 = (const float*)d_in[1];
  const float* b1 = (const float*)d_in[2];
  const float* W2 = (const float*)d_in[3];
  const float* b2 = (const float*)d_in[4];
  const float* W3 = (const float*)d_in[5];
  const float* b3 = (const float*)d_in[6];
  const float* temp = (const float*)d_in[7];
  (void)in_sizes; (void)n_in; (void)out_size; (void)ws_size;

  float* ws = (float*)d_ws;
  float* h  = ws;                                       // B*N*D
  float* sq = h + (size_t)BB * NN * DD;                 // B*N
  float* pk = sq + (size_t)BB * NN;                     // B*N*CH*K
  int*   pj = (int*)(pk + (size_t)BB * NN * CH * KK);   // B*N*CH*K
  float* out = (float*)d_out;

  k_mlp<<<BB * NN / 64, 256, 0, stream>>>(x, W1, b1, W2, b2, W3, b3, h, sq);
  k_disttopk<<<BB * (NN / 64) * CH, 256, 0, stream>>>(h, sq, temp, pk, pj);
  k_final<<<BB * NN / 256, 256, 0, stream>>>(h, pk, pj, temp, out);
}

// Round 7
// 301.300 us; speedup vs baseline: 1.6829x; 1.0231x over previous
//
#include <hip/hip_runtime.h>
#include <math.h>

#define BB 4
#define NN 4096
#define DD 64
#define KK 8
#define CH 4                    // j-chunks per row: grid = 4*64*4 = 1024 blocks
#define NT ((NN / CH) / 64)     // 16 j-tiles per block

#if defined(__has_builtin)
#if __has_builtin(__builtin_amdgcn_fmed3f)
#define FMED3(a, x, b) __builtin_amdgcn_fmed3f((x), (a), (b))
#endif
#endif
#ifndef FMED3
#define FMED3(a, x, b) fminf(fmaxf((a), (x)), (b))
#endif

__device__ __forceinline__ float tau_of(const float* __restrict__ temp) {
  float tc = temp[0];
  tc = fminf(fmaxf(tc, -5.0f), 5.0f);
  return expf(tc);
}

// Branch-free positional insert into sorted (ascending) top-8.
// All updates read OLD values -> fully parallel (no serial swap chain).
// key >= kk[7] is a provable no-op. Equal keys place AFTER incumbents,
// which matches strict-insert semantics under ascending-j arrival.
// NOTE: reference-to-1-D-array signature is load-bearing (SROA).
__device__ __forceinline__ void ins_med3(float (&kk)[KK], int (&kj)[KK], float key, int j) {
  const bool l0 = key < kk[0], l1 = key < kk[1], l2 = key < kk[2], l3 = key < kk[3];
  const bool l4 = key < kk[4], l5 = key < kk[5], l6 = key < kk[6], l7 = key < kk[7];
  kj[7] = l6 ? kj[6] : (l7 ? j : kj[7]);  kk[7] = FMED3(kk[6], key, kk[7]);
  kj[6] = l5 ? kj[5] : (l6 ? j : kj[6]);  kk[6] = FMED3(kk[5], key, kk[6]);
  kj[5] = l4 ? kj[4] : (l5 ? j : kj[5]);  kk[5] = FMED3(kk[4], key, kk[5]);
  kj[4] = l3 ? kj[3] : (l4 ? j : kj[4]);  kk[4] = FMED3(kk[3], key, kk[4]);
  kj[3] = l2 ? kj[2] : (l3 ? j : kj[3]);  kk[3] = FMED3(kk[2], key, kk[3]);
  kj[2] = l1 ? kj[1] : (l2 ? j : kj[2]);  kk[2] = FMED3(kk[1], key, kk[2]);
  kj[1] = l0 ? kj[0] : (l1 ? j : kj[1]);  kk[1] = FMED3(kk[0], key, kk[1]);
  kj[0] = l0 ? j : kj[0];                 kk[0] = fminf(kk[0], key);
}

// lexicographic (key asc, idx asc) insertion — arrival order independent.
__device__ __forceinline__ void ins_lex(float (&kk)[KK], int (&kj)[KK], float key, int j) {
  if (key < kk[KK - 1] || (key == kk[KK - 1] && j < kj[KK - 1])) {
    kk[KK - 1] = key; kj[KK - 1] = j;
#pragma unroll
    for (int m = KK - 1; m > 0; --m) {
      bool sw = (kk[m] < kk[m - 1]) || (kk[m] == kk[m - 1] && kj[m] < kj[m - 1]);
      if (sw) {
        float tk = kk[m]; kk[m] = kk[m - 1]; kk[m - 1] = tk;
        int tj = kj[m]; kj[m] = kj[m - 1]; kj[m - 1] = tj;
      }
    }
  }
}

__device__ __forceinline__ void scatter16(float (*dst)[64], int dc, int col,
                                          const float4& a, const float4& b,
                                          const float4& c, const float4& d) {
  dst[dc + 0][col] = a.x; dst[dc + 1][col] = a.y; dst[dc + 2][col] = a.z; dst[dc + 3][col] = a.w;
  dst[dc + 4][col] = b.x; dst[dc + 5][col] = b.y; dst[dc + 6][col] = b.z; dst[dc + 7][col] = b.w;
  dst[dc + 8][col] = c.x; dst[dc + 9][col] = c.y; dst[dc + 10][col] = c.z; dst[dc + 11][col] = c.w;
  dst[dc + 12][col] = d.x; dst[dc + 13][col] = d.y; dst[dc + 14][col] = d.z; dst[dc + 15][col] = d.w;
}

// ---------------- Kernel 1: MLP (3 layers) + row squared norms ----------------
__device__ __forceinline__ void mlp_layer(const float (*bin)[68], float (*bout)[68],
                                          float (*wT)[68], float* bias,
                                          const float* __restrict__ Wg,
                                          const float* __restrict__ bg,
                                          bool dorelu, int t) {
  const int rr = t >> 2;
  const int dc = (t & 3) << 4;
  {
    const float* wsrc = Wg + rr * DD + dc;
#pragma unroll
    for (int q = 0; q < 16; ++q) wT[dc + q][rr] = wsrc[q];  // wT[i][o] = W[o][i]
    if (t < DD) bias[t] = bg[t];
  }
  __syncthreads();
  const int tg = t & 15, og = t >> 4;
  float acc[4][4];
#pragma unroll
  for (int r = 0; r < 4; ++r)
#pragma unroll
    for (int c = 0; c < 4; ++c) acc[r][c] = 0.f;
#pragma unroll 4
  for (int i = 0; i < DD; ++i) {
    const float4 av = *reinterpret_cast<const float4*>(&bin[i][tg << 2]);
    const float4 wv = *reinterpret_cast<const float4*>(&wT[i][og << 2]);
    float aa[4] = {av.x, av.y, av.z, av.w};
    float ww[4] = {wv.x, wv.y, wv.z, wv.w};
#pragma unroll
    for (int r = 0; r < 4; ++r)
#pragma unroll
      for (int c = 0; c < 4; ++c) acc[r][c] += aa[r] * ww[c];
  }
#pragma unroll
  for (int r = 0; r < 4; ++r)
#pragma unroll
    for (int c = 0; c < 4; ++c) {
      float v = acc[r][c] + bias[(og << 2) + c];
      if (dorelu) v = fmaxf(v, 0.f);
      bout[(og << 2) + c][(tg << 2) + r] = v;  // transposed for next layer
    }
  __syncthreads();
}

__global__ __launch_bounds__(256) void k_mlp(
    const float* __restrict__ x,
    const float* __restrict__ W1, const float* __restrict__ b1,
    const float* __restrict__ W2, const float* __restrict__ b2,
    const float* __restrict__ W3, const float* __restrict__ b3,
    float* __restrict__ h, float* __restrict__ sqo) {
  __shared__ float bufA[DD][68];
  __shared__ float bufB[DD][68];
  __shared__ float wT[DD][68];
  __shared__ float bias[DD];
  const int t = threadIdx.x;
  const size_t tok0 = (size_t)blockIdx.x * 64;
  const int rr = t >> 2;
  const int dc = (t & 3) << 4;
  {
    const float* src = x + (tok0 + rr) * DD + dc;
#pragma unroll
    for (int q = 0; q < 16; ++q) bufA[dc + q][rr] = src[q];
  }
  mlp_layer(bufA, bufB, wT, bias, W1, b1, true, t);
  mlp_layer(bufB, bufA, wT, bias, W2, b2, true, t);
  mlp_layer(bufA, bufB, wT, bias, W3, b3, false, t);
  {
    float s = 0.f;
    float* dst = h + (tok0 + rr) * DD + dc;
#pragma unroll
    for (int q = 0; q < 16; ++q) {
      float v = bufB[dc + q][rr];
      dst[q] = v;
      s += v * v;
    }
    s += __shfl_xor(s, 1);
    s += __shfl_xor(s, 2);
    if ((t & 3) == 0) sqo[tok0 + rr] = s;
  }
}

// ------- Kernel 2: fused distance tiles + per-row top-8, register lists -------
// 2x8 register tile per thread: 2 rows (r0, r0+1) x 8 cols (c0..c0+7).
// Two named top-8 lists per thread; branchless med3 insert, unconditional.
__global__ __launch_bounds__(256, 3) void k_disttopk(
    const float* __restrict__ h, const float* __restrict__ sq,
    const float* __restrict__ temp,
    float* __restrict__ pk, int* __restrict__ pj) {
  // LDS (33 KB): hiT [64][64] @0 | hjT [64][64] @16384 | sqj @32768
  // merge reuse: dK @0 (16KB), dJ @16384 (16KB); then oK @0 (4KB), oJ @4096 (4KB)
  __shared__ __align__(16) char smem[16384 + 16384 + 256];
  float (*hiT)[64] = (float (*)[64])(smem);
  float (*hjT)[64] = (float (*)[64])(smem + 16384);
  float* sqjS = (float*)(smem + 32768);  // [64]

  const int t = threadIdx.x;
  const int bx = blockIdx.x;
  const int b = bx >> 8;
  const int rem = bx & 255;
  const int rt = rem >> 2;
  const int ch = rem & 3;
  const int i0 = rt << 6;
  const int jbase = ch * (NN / CH);
  const float* hb = h + (size_t)b * NN * DD;
  const float* sqb = sq + b * NN;
  const float tau = tau_of(temp);

  const int rg = t >> 3;        // 0..31
  const int cg = t & 7;         // 0..7
  const int r0 = rg << 1;       // even row
  const int c0 = cg << 3;       // col block of 8
  const int rr = t >> 2;        // staging: token within tile
  const int dc = (t & 3) << 4;  // staging: 16-float chunk

  // stage hiT and tile 0 of hjT (transposed [d][tok])
  {
    const float* src = hb + (size_t)(i0 + rr) * DD + dc;
    float4 f0 = *(const float4*)(src);
    float4 f1 = *(const float4*)(src + 4);
    float4 f2 = *(const float4*)(src + 8);
    float4 f3 = *(const float4*)(src + 12);
    scatter16(hiT, dc, rr, f0, f1, f2, f3);
  }
  {
    const float* src = hb + (size_t)(jbase + rr) * DD + dc;
    float4 f0 = *(const float4*)(src);
    float4 f1 = *(const float4*)(src + 4);
    float4 f2 = *(const float4*)(src + 8);
    float4 f3 = *(const float4*)(src + 12);
    scatter16(hjT, dc, rr, f0, f1, f2, f3);
    if (t < 64) sqjS[t] = sqb[jbase + t];
  }
  const float sqi0 = sqb[i0 + r0];
  const float sqi1 = sqb[i0 + r0 + 1];

  float kkA[KK]; int kjA[KK];
  float kkB[KK]; int kjB[KK];
#pragma unroll
  for (int m = 0; m < KK; ++m) {
    kkA[m] = 3.0e38f; kjA[m] = 0x7fffffff;
    kkB[m] = 3.0e38f; kjB[m] = 0x7fffffff;
  }

  __syncthreads();

  for (int jt = 0; jt < NT; ++jt) {
    const int j0 = jbase + (jt << 6);

    // T14: issue next tile's global loads now; LDS write after the compute+barrier
    float4 pf0, pf1, pf2, pf3; float psq = 0.f;
    const bool hasNext = (jt + 1 < NT);
    if (hasNext) {
      const float* src = hb + (size_t)(j0 + 64 + rr) * DD + dc;
      pf0 = *(const float4*)(src);
      pf1 = *(const float4*)(src + 4);
      pf2 = *(const float4*)(src + 8);
      pf3 = *(const float4*)(src + 12);
      if (t < 64) psq = sqb[j0 + 64 + t];
    }

    float acc[2][8];
#pragma unroll
    for (int r = 0; r < 2; ++r)
#pragma unroll
      for (int c = 0; c < 8; ++c) acc[r][c] = 0.f;
#pragma unroll 8
    for (int d = 0; d < DD; ++d) {
      const float2 a2 = *(const float2*)(&hiT[d][r0]);
      const float4 b0 = *(const float4*)(&hjT[d][c0]);
      const float4 b1 = *(const float4*)(&hjT[d][c0 + 4]);
      float bb[8] = {b0.x, b0.y, b0.z, b0.w, b1.x, b1.y, b1.z, b1.w};
#pragma unroll
      for (int c = 0; c < 8; ++c) {
        acc[0][c] += a2.x * bb[c];
        acc[1][c] += a2.y * bb[c];
      }
    }
    // epilogue: dist -> key -> branchless per-row top-8 (ascending j per thread).
    // fmaf(-2,acc,s2) == fsub(s2, fmul(2,acc)) exactly: 2*acc is exactly
    // representable, both round the exact value s2-2*acc once.
    const float4 sj0 = *(const float4*)(&sqjS[c0]);
    const float4 sj1 = *(const float4*)(&sqjS[c0 + 4]);
    float sj[8] = {sj0.x, sj0.y, sj0.z, sj0.w, sj1.x, sj1.y, sj1.z, sj1.w};
#pragma unroll
    for (int c = 0; c < 8; ++c) {
      const int j = j0 + c0 + c;
      float keyA = __fmul_rn(__builtin_fmaf(-2.0f, acc[0][c], __fadd_rn(sqi0, sj[c])), tau);
      ins_med3(kkA, kjA, keyA, j);
      float keyB = __fmul_rn(__builtin_fmaf(-2.0f, acc[1][c], __fadd_rn(sqi1, sj[c])), tau);
      ins_med3(kkB, kjB, keyB, j);
    }
    __syncthreads();  // everyone done reading hjT/sqjS
    if (hasNext) {
      scatter16(hjT, dc, rr, pf0, pf1, pf2, pf3);
      if (t < 64) sqjS[t] = psq;
    }
    __syncthreads();  // staged tile visible
  }

  // ---- merge per-row across the 8 cg-lists ----
  float* dK = (float*)(smem);            // [64][8][8] keys (16KB)
  int*   dJ = (int*)(smem + 16384);      // [64][8][8] idx  (16KB)
  // dump (hiT/hjT no longer needed; loop-end barrier covers us)
#pragma unroll
  for (int m = 0; m < KK; ++m) {
    dK[(r0 * 8 + cg) * KK + m] = kkA[m];
    dJ[(r0 * 8 + cg) * KK + m] = kjA[m];
    dK[((r0 + 1) * 8 + cg) * KK + m] = kkB[m];
    dJ[((r0 + 1) * 8 + cg) * KK + m] = kjB[m];
  }
  __syncthreads();

  // stage A: 128 threads, each merges 4 lists of one (row, half)
  float fk[KK]; int fj[KK];
#pragma unroll
  for (int m = 0; m < KK; ++m) { fk[m] = 3.0e38f; fj[m] = 0x7fffffff; }
  const int rowA = t >> 1, half = t & 1;
  if (t < 128) {
#pragma unroll
    for (int o = 0; o < 4; ++o) {
#pragma unroll
      for (int m = 0; m < KK; ++m) {
        ins_lex(fk, fj, dK[(rowA * 8 + half * 4 + o) * KK + m],
                        dJ[(rowA * 8 + half * 4 + o) * KK + m]);
      }
    }
  }
  __syncthreads();  // stage-A reads complete before overwrite
  float* oK = (float*)(smem);            // [64][2][8] keys (4KB)
  int*   oJ = (int*)(smem + 4096);       // [64][2][8] idx  (4KB)
  if (t < 128) {
#pragma unroll
    for (int m = 0; m < KK; ++m) {
      oK[(rowA * 2 + half) * KK + m] = fk[m];
      oJ[(rowA * 2 + half) * KK + m] = fj[m];
    }
  }
  __syncthreads();

  // stage B: 64 threads, merge the 2 halves, write out
  if (t < 64) {
    float gk[KK]; int gj[KK];
#pragma unroll
    for (int m = 0; m < KK; ++m) { gk[m] = 3.0e38f; gj[m] = 0x7fffffff; }
#pragma unroll
    for (int q = 0; q < 2; ++q) {
#pragma unroll
      for (int m = 0; m < KK; ++m) {
        ins_lex(gk, gj, oK[(t * 2 + q) * KK + m], oJ[(t * 2 + q) * KK + m]);
      }
    }
    const size_t base = ((size_t)(b * NN + i0 + t) * CH + ch) * KK;
#pragma unroll
    for (int m = 0; m < KK; ++m) { pk[base + m] = gk[m]; pj[base + m] = gj[m]; }
  }
}

// ------- Kernel 3: merge chunks, recompute dng, emit edges + logprobs -------
__global__ __launch_bounds__(256) void k_final(
    const float* __restrict__ h, const float* __restrict__ pk,
    const int* __restrict__ pj, const float* __restrict__ temp,
    float* __restrict__ out) {
  const int gid = blockIdx.x * 256 + threadIdx.x;  // 0..B*N-1
  const int b = gid >> 12;
  const int i = gid & (NN - 1);
  const float tau = tau_of(temp);

  float fk[KK]; int fj[KK];
#pragma unroll
  for (int m = 0; m < KK; ++m) { fk[m] = 3.0e38f; fj[m] = 0x7fffffff; }
  const size_t base = (size_t)(b * NN + i) * CH * KK;
#pragma unroll
  for (int s = 0; s < CH * KK; ++s) {
    ins_lex(fk, fj, pk[base + s], pj[base + s]);
  }

  const float* hi = h + (size_t)(b * NN + i) * DD;
  float4 xi[16];
#pragma unroll
  for (int q = 0; q < 16; ++q) xi[q] = *reinterpret_cast<const float4*>(hi + (q << 2));

  float* oute = out;
  float* outl = out + (size_t)BB * NN * KK * 2;
#pragma unroll
  for (int m = 0; m < KK; ++m) {
    const int j = fj[m];
    const float* hj = h + (size_t)(b * NN + j) * DD;
    float dng = 0.f;
#pragma unroll
    for (int q = 0; q < 16; ++q) {
      const float4 vj = *reinterpret_cast<const float4*>(hj + (q << 2));
      float dx = xi[q].x - vj.x; dng += dx * dx;
      float dy = xi[q].y - vj.y; dng += dy * dy;
      float dz = xi[q].z - vj.z; dng += dz * dz;
      float dw = xi[q].w - vj.w; dng += dw * dw;
    }
    const size_t e = (size_t)(b * NN + i) * KK + m;
    oute[e * 2 + 0] = (float)j;
    oute[e * 2 + 1] = (float)i;
    outl[e] = -__fmul_rn(dng, tau);
  }
}

extern "C" void kernel_launch(void* const* d_in, const int* in_sizes, int n_in,
                              void* d_out, int out_size, void* d_ws, size_t ws_size,
                              hipStream_t stream) {
  const float* x  = (const float*)d_in[0];
  const float* W1 = (const float*)d_in[1];
  const float* b1 = (const float*)d_in[2];
  const float* W2 = (const float*)d_in[3];
  const float* b2 = (const float*)d_in[4];
  const float* W3 = (const float*)d_in[5];
  const float* b3 = (const float*)d_in[6];
  const float* temp = (const float*)d_in[7];
  (void)in_sizes; (void)n_in; (void)out_size; (void)ws_size;

  float* ws = (float*)d_ws;
  float* h  = ws;                                       // B*N*D
  float* sq = h + (size_t)BB * NN * DD;                 // B*N
  float* pk = sq + (size_t)BB * NN;                     // B*N*CH*K
  int*   pj = (int*)(pk + (size_t)BB * NN * CH * KK);   // B*N*CH*K
  float* out = (float*)d_out;

  k_mlp<<<BB * NN / 64, 256, 0, stream>>>(x, W1, b1, W2, b2, W3, b3, h, sq);
  k_disttopk<<<BB * (NN / 64) * CH, 256, 0, stream>>>(h, sq, temp, pk, pj);
  k_final<<<BB * NN / 256, 256, 0, stream>>>(h, pk, pj, temp, out);
}